// Round 5
// baseline (301.270 us; speedup 1.0000x reference)
//
#include <hip/hip_runtime.h>
#include <hip/hip_bf16.h>

// MultiHeadedSelfAttention: B=4, S=2048, D=1024, H=16, W=64
//   1. cast x -> bf16 (scratch inside d_out, dead until final write)
//   2. cast Wq/Wk/Wv -> bf16; mask -> bf16 {0,1}
//   3. fused projection GEMM (q,k,v) -> head layouts in ws
//      (V rows for masked keys are zeroed -> mask folds out of softmax)
//   4. flash attention, 32x32 MFMA, swapped QK^T, in-register P exchange
//      via v_cvt_pk_bf16_f32 + v_permlane32_swap_b32 (no P through LDS),
//      row-sums l via mask-vector MFMA on the matrix pipe.
// K/V LDS tiles XOR-swizzled (elem ^ ((row&7)<<3)) via pre-swizzled global
// source columns (global_load_lds writes linearly; same involution on read).
// LDS = 32KB, grid = 1024 blocks = 4/CU fully resident.

#define NB 4
#define NS 2048
#define ND 1024
#define NH 16
#define NW 64

typedef __bf16 bf16;
typedef __bf16 bf16x2 __attribute__((ext_vector_type(2)));
typedef __bf16 bf16x4 __attribute__((ext_vector_type(4)));
typedef __bf16 bf16x8 __attribute__((ext_vector_type(8)));
typedef float f32x4 __attribute__((ext_vector_type(4)));
typedef float f32x16 __attribute__((ext_vector_type(16)));
typedef unsigned u32x4 __attribute__((ext_vector_type(4)));

__device__ __forceinline__ void gld_lds16(const void* g, void* l) {
  __builtin_amdgcn_global_load_lds(
      (const __attribute__((address_space(1))) void*)g,
      (__attribute__((address_space(3))) void*)l, 16, 0, 0);
}

__device__ __forceinline__ unsigned pack2(float lo, float hi) {
  bf16x2 t;
  t[0] = (bf16)lo;
  t[1] = (bf16)hi;
  return __builtin_bit_cast(unsigned, t);
}

__global__ void cast_f32_bf16(const float* __restrict__ src,
                              bf16* __restrict__ dst, int n) {
  int i = (blockIdx.x * blockDim.x + threadIdx.x) * 8;
  int stride = gridDim.x * blockDim.x * 8;
  for (; i < n; i += stride) {
    float4 a = *reinterpret_cast<const float4*>(src + i);
    float4 b = *reinterpret_cast<const float4*>(src + i + 4);
    bf16x8 o;
    o[0] = (bf16)a.x; o[1] = (bf16)a.y; o[2] = (bf16)a.z; o[3] = (bf16)a.w;
    o[4] = (bf16)b.x; o[5] = (bf16)b.y; o[6] = (bf16)b.z; o[7] = (bf16)b.w;
    *reinterpret_cast<bf16x8*>(dst + i) = o;
  }
}

// one launch for all three weight matrices (blockIdx.y selects)
__global__ void cast_weights(const float* __restrict__ a,
                             const float* __restrict__ b,
                             const float* __restrict__ c,
                             bf16* __restrict__ dst) {
  const int n = ND * ND;
  const int which = blockIdx.y;
  const float* src = (which == 0) ? a : ((which == 1) ? b : c);
  bf16* d = dst + (size_t)which * n;
  int i = (blockIdx.x * blockDim.x + threadIdx.x) * 8;
  float4 u = *reinterpret_cast<const float4*>(src + i);
  float4 v = *reinterpret_cast<const float4*>(src + i + 4);
  bf16x8 o;
  o[0] = (bf16)u.x; o[1] = (bf16)u.y; o[2] = (bf16)u.z; o[3] = (bf16)u.w;
  o[4] = (bf16)v.x; o[5] = (bf16)v.y; o[6] = (bf16)v.z; o[7] = (bf16)v.w;
  *reinterpret_cast<bf16x8*>(d + i) = o;
}

__global__ void mask_to_bf16(const int* __restrict__ mask,
                             bf16* __restrict__ mb, int n) {
  int i = blockIdx.x * blockDim.x + threadIdx.x;
  if (i < n) mb[i] = (bf16)(mask[i] ? 1.0f : 0.0f);
}

// ---------------- projection GEMM ----------------
__global__ __launch_bounds__(256) void proj_kernel(
    const bf16* __restrict__ xb,
    const bf16* __restrict__ wq,
    const bf16* __restrict__ wk,
    const bf16* __restrict__ wv,
    const float* __restrict__ bq,
    const float* __restrict__ bk,
    const float* __restrict__ bv,
    const int* __restrict__ mask,
    bf16* __restrict__ qh,
    bf16* __restrict__ kh,
    bf16* __restrict__ vt) {
  const int mode = blockIdx.z;
  const bf16* wmat = (mode == 0) ? wq : ((mode == 1) ? wk : wv);
  const float* bias = (mode == 0) ? bq : ((mode == 1) ? bk : bv);

  __shared__ bf16 a_lds[128][64];
  __shared__ bf16 b_lds[128][64];

  const int tid = threadIdx.x;
  const int wave = tid >> 6;
  const int lane = tid & 63;
  const int wr = wave >> 1, wc = wave & 1;
  const int m0 = blockIdx.x * 128;
  const int n0 = blockIdx.y * 128;

  f32x4 acc[4][4] = {};

  const int srow = tid >> 3;
  const int scol = (tid & 7) * 8;
  const int sw_scol = scol ^ ((srow & 7) << 3);
  const int xr = (lane & 7) << 3;
  const int lr = lane & 15;
  const int kq = (lane >> 4) * 8;

  for (int k0 = 0; k0 < 1024; k0 += 64) {
#pragma unroll
    for (int c = 0; c < 4; ++c) {
      int row = srow + c * 32;
      gld_lds16(xb + (size_t)(m0 + row) * 1024 + k0 + sw_scol, &a_lds[row][scol]);
      gld_lds16(wmat + (size_t)(n0 + row) * 1024 + k0 + sw_scol, &b_lds[row][scol]);
    }
    __syncthreads();
#pragma unroll
    for (int kk = 0; kk < 64; kk += 32) {
      bf16x8 af[4], bfr[4];
      const int col = (kk + kq) ^ xr;
#pragma unroll
      for (int mf = 0; mf < 4; ++mf)
        af[mf] = *reinterpret_cast<const bf16x8*>(&a_lds[wr * 64 + mf * 16 + lr][col]);
#pragma unroll
      for (int nf = 0; nf < 4; ++nf)
        bfr[nf] = *reinterpret_cast<const bf16x8*>(&b_lds[wc * 64 + nf * 16 + lr][col]);
#pragma unroll
      for (int mf = 0; mf < 4; ++mf)
#pragma unroll
        for (int nf = 0; nf < 4; ++nf)
          acc[mf][nf] = __builtin_amdgcn_mfma_f32_16x16x32_bf16(af[mf], bfr[nf], acc[mf][nf], 0, 0, 0);
    }
    __syncthreads();
  }

  // epilogue: +bias, cast bf16, scatter to head layout
  if (mode == 2) {
    // V transposed per head, masked keys zeroed
    float msk[4][4];
#pragma unroll
    for (int mf = 0; mf < 4; ++mf) {
      const int i0 = m0 + wr * 64 + mf * 16 + (lane >> 4) * 4;
      const int b = i0 >> 11, s = i0 & 2047;
      const int4 mm = *reinterpret_cast<const int4*>(mask + b * NS + s);
      msk[mf][0] = mm.x ? 1.f : 0.f;
      msk[mf][1] = mm.y ? 1.f : 0.f;
      msk[mf][2] = mm.z ? 1.f : 0.f;
      msk[mf][3] = mm.w ? 1.f : 0.f;
    }
#pragma unroll
    for (int nf = 0; nf < 4; ++nf) {
      const int j = n0 + wc * 64 + nf * 16 + lr;
      const float bj = bias[j];
      const int h = j >> 6, w = j & 63;
#pragma unroll
      for (int mf = 0; mf < 4; ++mf) {
        const int i0 = m0 + wr * 64 + mf * 16 + (lane >> 4) * 4;
        const int b = i0 >> 11, s = i0 & 2047;
        bf16x4 pk;
#pragma unroll
        for (int r = 0; r < 4; ++r)
          pk[r] = (bf16)((acc[mf][nf][r] + bj) * msk[mf][r]);
        *reinterpret_cast<bf16x4*>(&vt[(((size_t)(b * NH + h)) * NW + w) * NS + s]) = pk;
      }
    }
  } else {
    bf16* dst = (mode == 0) ? qh : kh;
#pragma unroll
    for (int nf = 0; nf < 4; ++nf) {
      const int j = n0 + wc * 64 + nf * 16 + lr;
      const float bj = bias[j];
      const int h = j >> 6, w = j & 63;
#pragma unroll
      for (int mf = 0; mf < 4; ++mf) {
        const int i0 = m0 + wr * 64 + mf * 16 + (lane >> 4) * 4;
        const int b = i0 >> 11, s = i0 & 2047;
#pragma unroll
        for (int r = 0; r < 4; ++r)
          dst[(((size_t)(b * NH + h)) * NS + s + r) * NW + w] = (bf16)(acc[mf][nf][r] + bj);
      }
    }
  }
}

// ---------------- flash attention ----------------
// grid: (S/128, B*H); block: 256 (4 waves, 32 q-rows per wave)
// 32x32x16 MFMA; P never touches LDS (cvt_pk + permlane32_swap).
__global__ __launch_bounds__(256, 4) void attn_kernel(
    const bf16* __restrict__ qh,
    const bf16* __restrict__ kh,
    const bf16* __restrict__ vt,
    const bf16* __restrict__ mb16,
    float* __restrict__ out) {
  __shared__ bf16 k_lds[2][64][64];
  __shared__ bf16 v_lds[2][64][64];  // [w][t]

  const int tid = threadIdx.x;
  const int wave = tid >> 6;
  const int lane = tid & 63;
  const int lq = lane & 31;   // q column (and lds row index)
  const int hi = lane >> 5;   // half-wave select
  const int xr = (lq & 7) << 3;
  const int bh = blockIdx.y;
  const int b = bh >> 4;
  const int q0 = blockIdx.x * 128;
  const size_t headoff = (size_t)bh * NS * NW;

  // Q fragments (B operand): Q[q = q0+wave*32+lq][w = m*16 + hi*8 + j]
  bf16x8 qf[4];
  {
    const bf16* qp = qh + headoff + (size_t)(q0 + wave * 32 + lq) * NW + hi * 8;
#pragma unroll
    for (int m = 0; m < 4; ++m)
      qf[m] = *reinterpret_cast<const bf16x8*>(qp + m * 16);
  }

  f32x16 o0 = {}, o1 = {}, lt = {};
  const float SC2 = 0.18033688011112042f;  // (1/8) * log2(e)
  const bf16* mp = mb16 + b * NS;

  const int srow = tid >> 3;
  const int scol = (tid & 7) * 8;
  const int sw_scol = scol ^ ((srow & 7) << 3);

#define STAGE(buf, kt)                                                          \
  {                                                                             \
    _Pragma("unroll") for (int c = 0; c < 2; ++c) {                             \
      const int row = srow + c * 32;                                            \
      gld_lds16(kh + headoff + (size_t)((kt) + row) * NW + sw_scol,             \
                &k_lds[buf][row][scol]);                                        \
      gld_lds16(vt + headoff + (size_t)row * NS + (kt) + sw_scol,               \
                &v_lds[buf][row][scol]);                                        \
    }                                                                           \
  }

  // QK^T for one 32-key group -> P fragments PA0 (keys +0..15), PA1 (+16..31)
#define QK_GROUP(G, PA0, PA1)                                                   \
  {                                                                             \
    f32x16 s = {};                                                              \
    __builtin_amdgcn_s_setprio(1);                                              \
    _Pragma("unroll") for (int m = 0; m < 4; ++m) {                             \
      bf16x8 kf = *reinterpret_cast<const bf16x8*>(                             \
          &k_lds[cur][(G) * 32 + lq][(m * 16 + hi * 8) ^ xr]);                  \
      s = __builtin_amdgcn_mfma_f32_32x32x16_bf16(kf, qf[m], s, 0, 0, 0);       \
    }                                                                           \
    __builtin_amdgcn_s_setprio(0);                                              \
    unsigned w[8];                                                              \
    _Pragma("unroll") for (int j = 0; j < 8; ++j)                               \
        w[j] = pack2(exp2f(s[2 * j] * SC2), exp2f(s[2 * j + 1] * SC2));         \
    asm("v_permlane32_swap_b32 %0, %1" : "+v"(w[0]), "+v"(w[2]));               \
    asm("v_permlane32_swap_b32 %0, %1" : "+v"(w[1]), "+v"(w[3]));               \
    asm("v_permlane32_swap_b32 %0, %1" : "+v"(w[4]), "+v"(w[6]));               \
    asm("v_permlane32_swap_b32 %0, %1" : "+v"(w[5]), "+v"(w[7]));               \
    u32x4 u0 = {w[0], w[1], w[2], w[3]};                                        \
    u32x4 u1 = {w[4], w[5], w[6], w[7]};                                        \
    PA0 = __builtin_bit_cast(bf16x8, u0);                                       \
    PA1 = __builtin_bit_cast(bf16x8, u1);                                       \
  }

  // PV + row-sum for one group: 6 MFMA
#define PV_GROUP(G, PA0, PA1)                                                   \
  {                                                                             \
    const bf16* mpk = mp + kt + (G) * 32 + hi * 8;                              \
    bf16x8 mf0 = *reinterpret_cast<const bf16x8*>(mpk);                         \
    bf16x8 mf1 = *reinterpret_cast<const bf16x8*>(mpk + 16);                    \
    __builtin_amdgcn_s_setprio(1);                                              \
    lt = __builtin_amdgcn_mfma_f32_32x32x16_bf16(PA0, mf0, lt, 0, 0, 0);        \
    lt = __builtin_amdgcn_mfma_f32_32x32x16_bf16(PA1, mf1, lt, 0, 0, 0);        \
    bf16x8 v00 = *reinterpret_cast<const bf16x8*>(                              \
        &v_lds[cur][lq][((G) * 32 + hi * 8) ^ xr]);                             \
    o0 = __builtin_amdgcn_mfma_f32_32x32x16_bf16(PA0, v00, o0, 0, 0, 0);        \
    bf16x8 v01 = *reinterpret_cast<const bf16x8*>(                              \
        &v_lds[cur][lq][((G) * 32 + 16 + hi * 8) ^ xr]);                        \
    o0 = __builtin_amdgcn_mfma_f32_32x32x16_bf16(PA1, v01, o0, 0, 0, 0);        \
    bf16x8 v10 = *reinterpret_cast<const bf16x8*>(                              \
        &v_lds[cur][32 + lq][((G) * 32 + hi * 8) ^ xr]);                        \
    o1 = __builtin_amdgcn_mfma_f32_32x32x16_bf16(PA0, v10, o1, 0, 0, 0);        \
    bf16x8 v11 = *reinterpret_cast<const bf16x8*>(                              \
        &v_lds[cur][32 + lq][((G) * 32 + 16 + hi * 8) ^ xr]);                   \
    o1 = __builtin_amdgcn_mfma_f32_32x32x16_bf16(PA1, v11, o1, 0, 0, 0);        \
    __builtin_amdgcn_s_setprio(0);                                              \
  }

  STAGE(0, 0);
  __syncthreads();

  int cur = 0;
  for (int kt = 0; kt < NS; kt += 64) {
    if (kt + 64 < NS) STAGE(cur ^ 1, kt + 64);
    bf16x8 pa0, pa1, pa2, pa3;
    QK_GROUP(0, pa0, pa1);
    PV_GROUP(0, pa0, pa1);
    QK_GROUP(1, pa2, pa3);
    PV_GROUP(1, pa2, pa3);
    __syncthreads();
    cur ^= 1;
  }

  // out[b][s][h*64+w] = o / l ; D rows: (r&3)+8*(r>>2)+4*hi, col lq
  const int h = bh & 15;
  float* op = out + ((size_t)b * NS) * ND + h * NW;
#pragma unroll
  for (int r = 0; r < 16; ++r) {
    const int sq = q0 + wave * 32 + (r & 3) + 8 * (r >> 2) + 4 * hi;
    const float inv = 1.0f / lt[r];
    op[(size_t)sq * ND + lq] = o0[r] * inv;
    op[(size_t)sq * ND + 32 + lq] = o1[r] * inv;
  }
#undef STAGE
#undef QK_GROUP
#undef PV_GROUP
}

extern "C" void kernel_launch(void* const* d_in, const int* in_sizes, int n_in,
                              void* d_out, int out_size, void* d_ws, size_t ws_size,
                              hipStream_t stream) {
  const float* x = (const float*)d_in[0];
  const int* mask = (const int*)d_in[1];
  const float* Wq = (const float*)d_in[2];
  const float* bq = (const float*)d_in[3];
  const float* Wk = (const float*)d_in[4];
  const float* bk = (const float*)d_in[5];
  const float* Wv = (const float*)d_in[6];
  const float* bv = (const float*)d_in[7];
  float* out = (float*)d_out;

  char* ws = (char*)d_ws;
  bf16* wqb = (bf16*)(ws + (size_t)(0) * (1 << 20));
  bf16* wkb = (bf16*)(ws + (size_t)(2) * (1 << 20));
  bf16* wvb = (bf16*)(ws + (size_t)(4) * (1 << 20));
  bf16* qhb = (bf16*)(ws + (size_t)(6) * (1 << 20));   // 16MB
  bf16* khb = (bf16*)(ws + (size_t)(22) * (1 << 20));  // 16MB
  bf16* vtb = (bf16*)(ws + (size_t)(38) * (1 << 20));  // 16MB
  bf16* mb16 = (bf16*)(ws + (size_t)(54) * (1 << 20)); // 16KB
  // bf16 copy of x lives in d_out's first 16MB (dead until attn writes)
  bf16* xb = (bf16*)d_out;

  cast_f32_bf16<<<2048, 256, 0, stream>>>(x, xb, NB * NS * ND);
  cast_weights<<<dim3(512, 3), 256, 0, stream>>>(Wq, Wk, Wv, wqb);
  mask_to_bf16<<<32, 256, 0, stream>>>(mask, mb16, NB * NS);
  proj_kernel<<<dim3(64, 8, 3), 256, 0, stream>>>(xb, wqb, wkb, wvb, bq, bk, bv,
                                                  mask, qhb, khb, vtb);
  attn_kernel<<<dim3(NS / 128, NB * NH), 256, 0, stream>>>(qhb, khb, vtb, mb16, out);
}